// Round 15
// baseline (161.723 us; speedup 1.0000x reference)
//
#include <hip/hip_runtime.h>
#include <hip/hip_bf16.h>
#include <math.h>

// ---------------------------------------------------------------------------
// SupConLoss on MI355X.
// out = 0.5*CE(predicts,targets) + 0.5*nt_xent(Anorm, temp=0.1)
//       + 0.25*nt_xent2(Anorm, temp=0.05)
// Round 15: fp8 packed register-direct gemm with SPLIT-K x4 (4 waves per
// 64x64 tile, 6 K-iters each; partials merged via two 16 KB LDS buffers in
// a 2-step tree; epilogue split 4 ways). Round 14's split-K x2 cut gemm
// 45.7->~30 by doubling waves/CU; this halves the per-wave latency chain
// again. Tail restructured: class histogram in k_prep block 0, per-row
// stats folded into k_merge with 3 atomics/block, k_final is now a
// 10-element formula (the old single-block scan was ~12 us).
// NOTE: ~43 us of total is the harness's 268 MB d_ws re-poison fill
// (visible as fillBufferAligned in round 14's profile) — not addressable.
// Exp sums unshifted (|exponent|<=20, fp32-safe); reference row-max shift
// applied exactly in merge: S_j = s2_raw * exp(-20*vmax_j).
// ---------------------------------------------------------------------------

typedef __attribute__((ext_vector_type(4))) float f32x4;
typedef long long ll;

__device__ __forceinline__ float blockReduceSum(float v, float* sbuf) {
#pragma unroll
  for (int o = 32; o > 0; o >>= 1) v += __shfl_down(v, o, 64);
  int lane = threadIdx.x & 63;
  int w = threadIdx.x >> 6;
  __syncthreads();
  if (lane == 0) sbuf[w] = v;
  __syncthreads();
  return sbuf[0] + sbuf[1] + sbuf[2] + sbuf[3];
}

// --- 1. fused normalize + fp8 fragment-pack + per-row CE + (blk0) setup ----
// Packed layout: 8B chunk index = ((strip*KB + kb)*4 + mt)*64 + lane
//   holds row = strip*64 + mt*16 + (lane&15), k = kb*32 + (lane>>4)*8 .. +7.
__global__ void k_prep(const float* __restrict__ X, const float* __restrict__ P,
                       const int* __restrict__ tgt, uint2* __restrict__ Pk,
                       float* __restrict__ ce_row, float* __restrict__ classSg,
                       int* __restrict__ classCntg, float* __restrict__ sums,
                       int N, int D, int C) {
  __shared__ float sbuf[8];
  int row = blockIdx.x;
  const float* x = X + (size_t)row * D;
  float ss = 0.f;
  const float4* x4 = (const float4*)x;
  for (int j = threadIdx.x; j < (D >> 2); j += blockDim.x) {
    float4 v = x4[j];
    ss += v.x * v.x + v.y * v.y + v.z * v.z + v.w * v.w;
  }
  ss = blockReduceSum(ss, sbuf);
  float inv = 1.0f / fmaxf(sqrtf(ss), 1e-12f);

  const int KB = D / 32;           // 24
  const int strip = row >> 6;
  const int mt = (row >> 4) & 3;
  const int l4 = row & 15;
  const int nchunk = D / 8;        // 96
  for (int c = threadIdx.x; c < nchunk; c += blockDim.x) {
    int kb = c >> 2;
    int lsub = c & 3;
    int k0 = kb * 32 + lsub * 8;
    float v[8];
#pragma unroll
    for (int j = 0; j < 8; ++j) v[j] = x[k0 + j] * inv;
    unsigned int r0 = 0, r1 = 0;
    r0 = __builtin_amdgcn_cvt_pk_fp8_f32(v[0], v[1], r0, 0);
    r0 = __builtin_amdgcn_cvt_pk_fp8_f32(v[2], v[3], r0, 1);
    r1 = __builtin_amdgcn_cvt_pk_fp8_f32(v[4], v[5], r1, 0);
    r1 = __builtin_amdgcn_cvt_pk_fp8_f32(v[6], v[7], r1, 1);
    int lane = l4 + 16 * lsub;
    size_t chunk = ((size_t)(strip * KB + kb) * 4 + mt) * 64 + lane;
    Pk[chunk] = make_uint2(r0, r1);
  }
  if (threadIdx.x == 0) {
    const float* p = P + (size_t)row * C;
    float m = -INFINITY;
    for (int c = 0; c < C; ++c) m = fmaxf(m, p[c]);
    float s = 0.f;
    for (int c = 0; c < C; ++c) s += expf(p[c] - m);
    int t = tgt[row];
    ce_row[row] = -(p[t] - m - logf(s));
  }
  // block 0: zero accumulators + histogram targets (consumed by k_merge)
  if (blockIdx.x == 0) {
    __shared__ int hc[32];
    if (threadIdx.x < 32) hc[threadIdx.x] = 0;
    __syncthreads();
    for (int i = threadIdx.x; i < N; i += blockDim.x)
      atomicAdd(&hc[tgt[i]], 1);
    __syncthreads();
    if (threadIdx.x < C) {
      classCntg[threadIdx.x] = hc[threadIdx.x];
      classSg[threadIdx.x] = 0.f;
    }
    if (threadIdx.x < 2) sums[threadIdx.x] = 0.f;
  }
}

// --- 2. 4-wave split-K 64x64 fused symmetric GEMM + stats, fp8 packed ------
// part layout: float4 part[N][NB]; (psum, s1_raw, s2_raw, m2=20*vmax_neg).
__global__ __launch_bounds__(256) void k_gemm_fused(
    const unsigned char* __restrict__ Pk, const int* __restrict__ lab,
    float4* __restrict__ part, int N, int K, int NB) {
  __shared__ f32x4 buf0[4][4][64];  // 16 KB
  __shared__ f32x4 buf1[4][4][64];  // 16 KB

  // triangular decode: bid -> (by, bx), by >= bx
  int bid = blockIdx.x;
  int by = (int)((sqrtf(8.f * (float)bid + 1.f) - 1.f) * 0.5f);
  while ((by + 1) * (by + 2) / 2 <= bid) ++by;
  while (by * (by + 1) / 2 > bid) --by;
  int bx = bid - by * (by + 1) / 2;

  const int t = threadIdx.x & 63;
  const int wv = threadIdx.x >> 6;  // 0..3
  const int rowBase = by * 64;
  const int colBase = bx * 64;
  const int KB = K / 32;        // 24
  const int KBq = KB >> 2;      // 6 per wave

  const int myLR = lab[rowBase + t];
  const int myLC = lab[colBase + t];

  // byte offsets: chunk = ((strip*KB+kb)*4+mt)*64 + lane, 8 bytes each;
  // this wave's K-quarter starts at kb = wv*KBq.
  const unsigned char* aP =
      Pk + ((size_t)by * KB * 4 * 64 + t) * 8 + (size_t)wv * KBq * 2048;
  const unsigned char* bP =
      Pk + ((size_t)bx * KB * 4 * 64 + t) * 8 + (size_t)wv * KBq * 2048;

  f32x4 acc[4][4] = {};
#pragma unroll 2
  for (int kb = 0; kb < KBq; ++kb) {
    ll af[4], bf[4];
    const unsigned char* ak = aP + (size_t)kb * 2048;
    const unsigned char* bk = bP + (size_t)kb * 2048;
#pragma unroll
    for (int mt = 0; mt < 4; ++mt) af[mt] = *(const ll*)(ak + mt * 512);
#pragma unroll
    for (int nt = 0; nt < 4; ++nt) bf[nt] = *(const ll*)(bk + nt * 512);
#pragma unroll
    for (int mt = 0; mt < 4; ++mt)
#pragma unroll
      for (int nt = 0; nt < 4; ++nt)
        acc[mt][nt] = __builtin_amdgcn_mfma_f32_16x16x32_fp8_fp8(
            af[mt], bf[nt], acc[mt][nt], 0, 0, 0);
  }

  // ---- 2-step tree exchange: buf0 = w0+w1, buf1 = w2+w3 ------------------
  if (wv == 0) {
#pragma unroll
    for (int mt = 0; mt < 4; ++mt)
#pragma unroll
      for (int nt = 0; nt < 4; ++nt) buf0[mt][nt][t] = acc[mt][nt];
  } else if (wv == 2) {
#pragma unroll
    for (int mt = 0; mt < 4; ++mt)
#pragma unroll
      for (int nt = 0; nt < 4; ++nt) buf1[mt][nt][t] = acc[mt][nt];
  }
  __syncthreads();
  if (wv == 1) {
#pragma unroll
    for (int mt = 0; mt < 4; ++mt)
#pragma unroll
      for (int nt = 0; nt < 4; ++nt) {
        acc[mt][nt] += buf0[mt][nt][t];
        buf0[mt][nt][t] = acc[mt][nt];
      }
  } else if (wv == 3) {
#pragma unroll
    for (int mt = 0; mt < 4; ++mt)
#pragma unroll
      for (int nt = 0; nt < 4; ++nt) {
        acc[mt][nt] += buf1[mt][nt][t];
        buf1[mt][nt][t] = acc[mt][nt];
      }
  }
  __syncthreads();

  // ---- epilogue: w0/w1 = A-side (mt pairs), w2/w3 = B-side (nt pairs) -----
  // element: row = mt*16 + (t>>4)*4 + r ; col = nt*16 + (t&15)
  int cl[4];
#pragma unroll
  for (int nt = 0; nt < 4; ++nt) cl[nt] = __shfl(myLC, nt * 16 + (t & 15), 64);
  const bool dg = (by == bx);

  if (wv < 2) {
    // full acc for mt in {2*wv, 2*wv+1}
    f32x4 fq[2][4];
#pragma unroll
    for (int mi = 0; mi < 2; ++mi) {
      int mt = wv * 2 + mi;
#pragma unroll
      for (int nt = 0; nt < 4; ++nt)
        fq[mi][nt] = buf0[mt][nt][t] + buf1[mt][nt][t];
    }
#pragma unroll
    for (int mi = 0; mi < 2; ++mi) {
      int mt = wv * 2 + mi;
#pragma unroll
      for (int r = 0; r < 4; ++r) {
        int rowL = mt * 16 + (t >> 4) * 4 + r;
        int lr = __shfl(myLR, rowL, 64);
        float ps = 0.f, s1 = 0.f, s2 = 0.f, vm = -1e30f;
#pragma unroll
        for (int nt = 0; nt < 4; ++nt) {
          float v = fq[mi][nt][r];
          int colL = nt * 16 + (t & 15);
          bool diag = dg && (rowL == colL);
          bool same = (lr == cl[nt]);
          float e10 = __expf(v * 10.f);
          float e20 = e10 * e10;
          s1 += diag ? 1.f : e10;
          ps += (same && !diag) ? v : 0.f;
          s2 += same ? 0.f : e20;
          vm = same ? vm : fmaxf(vm, v);
        }
#pragma unroll
        for (int o = 1; o < 16; o <<= 1) {
          ps += __shfl_xor(ps, o, 64);
          s1 += __shfl_xor(s1, o, 64);
          s2 += __shfl_xor(s2, o, 64);
          vm = fmaxf(vm, __shfl_xor(vm, o, 64));
        }
        if ((t & 15) == 0)
          part[(size_t)(rowBase + rowL) * NB + bx] =
              make_float4(ps, s1, s2, 20.f * vm);
      }
    }
  } else if (!dg) {
    // full acc for nt in {2*(wv-2), 2*(wv-2)+1}
    f32x4 fq[4][2];
#pragma unroll
    for (int ni = 0; ni < 2; ++ni) {
      int nt = (wv - 2) * 2 + ni;
#pragma unroll
      for (int mt = 0; mt < 4; ++mt)
        fq[mt][ni] = buf0[mt][nt][t] + buf1[mt][nt][t];
    }
#pragma unroll
    for (int ni = 0; ni < 2; ++ni) {
      int nt = (wv - 2) * 2 + ni;
      int lc = cl[nt];
      float ps = 0.f, s1 = 0.f, s2 = 0.f, vm = -1e30f;
#pragma unroll
      for (int mt = 0; mt < 4; ++mt)
#pragma unroll
        for (int r = 0; r < 4; ++r) {
          float v = fq[mt][ni][r];
          int rowL = mt * 16 + (t >> 4) * 4 + r;
          int lr = __shfl(myLR, rowL, 64);
          bool same = (lr == lc);
          float e10 = __expf(v * 10.f);
          s1 += e10;
          ps += same ? v : 0.f;
          s2 += same ? 0.f : e10 * e10;
          vm = same ? vm : fmaxf(vm, v);
        }
#pragma unroll
      for (int o = 16; o < 64; o <<= 1) {
        ps += __shfl_xor(ps, o, 64);
        s1 += __shfl_xor(s1, o, 64);
        s2 += __shfl_xor(s2, o, 64);
        vm = fmaxf(vm, __shfl_xor(vm, o, 64));
      }
      if ((t >> 4) == 0)
        part[(size_t)(colBase + nt * 16 + (t & 15)) * NB + by] =
            make_float4(ps, s1, s2, 20.f * vm);
    }
  }
}

// --- 3. merge partials per row + fold stats into global accumulators -------
__global__ void k_merge(const float4* __restrict__ part,
                        const float* __restrict__ ce_row,
                        const int* __restrict__ lab,
                        const int* __restrict__ classCntg,
                        float* __restrict__ classSg, float* __restrict__ sums,
                        int N, int NB) {
  __shared__ float pbuf[4][2];
  int lane = threadIdx.x & 63;
  int w = threadIdx.x >> 6;
  int row = blockIdx.x * 4 + w;
  float ps = 0.f, s1 = 0.f, s2 = 0.f, m2 = -1e30f;
  if (lane < NB) {
    float4 p = part[(size_t)row * NB + lane];
    ps = p.x; s1 = p.y; s2 = p.z; m2 = p.w;
  }
#pragma unroll
  for (int o = 32; o > 0; o >>= 1) {
    ps += __shfl_down(ps, o, 64);
    s1 += __shfl_down(s1, o, 64);
    s2 += __shfl_down(s2, o, 64);
    m2 = fmaxf(m2, __shfl_down(m2, o, 64));
  }
  if (lane == 0) {
    int l = lab[row];
    float Srow = (m2 < -1e29f) ? 0.f : s2 * expf(-m2);
    atomicAdd(&classSg[l], Srow);
    int pc = classCntg[l] - 1;
    float p1 = (pc > 0) ? ps * 10.f / (float)pc - logf(s1) : 0.f;
    pbuf[w][0] = ce_row[row];
    pbuf[w][1] = p1;
  }
  __syncthreads();
  if (threadIdx.x == 0) {
    atomicAdd(&sums[0], pbuf[0][0] + pbuf[1][0] + pbuf[2][0] + pbuf[3][0]);
    atomicAdd(&sums[1], pbuf[0][1] + pbuf[1][1] + pbuf[2][1] + pbuf[3][1]);
  }
}

// --- 4. finalize (tiny: 10-class formula) ----------------------------------
__global__ void k_final(const float* __restrict__ classSg,
                        const int* __restrict__ classCntg,
                        const float* __restrict__ sums,
                        float* __restrict__ out, int N, int C) {
  if (threadIdx.x == 0) {
    float totS = 0.f;
    for (int c = 0; c < C; ++c) totS += classSg[c];
    float l2sum = 0.f;
    for (int c = 0; c < C; ++c) {
      int cnt = classCntg[c];
      if (cnt >= 2) {
        float negs = (float)(N - cnt);
        float x = (totS - classSg[c]) / negs;
        l2sum += (float)cnt * logf(x + 1e-12f);
      }
    }
    float ce = sums[0] / (float)N;
    float ntx1 = -sums[1] / (float)N;
    float ntx2 = l2sum / (float)N;
    out[0] = 0.5f * ce + 0.5f * ntx1 + 0.25f * ntx2;
  }
}

extern "C" void kernel_launch(void* const* d_in, const int* in_sizes, int n_in,
                              void* d_out, int out_size, void* d_ws,
                              size_t ws_size, hipStream_t stream) {
  const float* X = (const float*)d_in[0];  // cls_feats [N,D]
  const float* P = (const float*)d_in[1];  // predicts  [N,C]
  const int* tgt = (const int*)d_in[2];    // targets   [N]
  float* out = (float*)d_out;

  int N = in_sizes[2];
  int D = in_sizes[0] / N;
  int C = in_sizes[1] / N;
  int NB = N / 64;

  char* ws = (char*)d_ws;
  uint2* Pk = (uint2*)ws;                        // N*D fp8 bytes, packed
  float4* part = (float4*)(ws + (size_t)N * D);  // N*NB float4
  float* ce_row = (float*)((char*)part + (size_t)N * NB * 16);
  float* classSg = ce_row + N;    // 32
  int* classCntg = (int*)(classSg + 32);  // 32
  float* sums = (float*)(classCntg + 32); // 2: sumCe, sumP1

  k_prep<<<N, 256, 0, stream>>>(X, P, tgt, Pk, ce_row, classSg, classCntg,
                                sums, N, D, C);
  int nblk = NB * (NB + 1) / 2;
  k_gemm_fused<<<nblk, 256, 0, stream>>>((const unsigned char*)Pk, tgt, part,
                                         N, D, NB);
  k_merge<<<N / 4, 256, 0, stream>>>(part, ce_row, tgt, classCntg, classSg,
                                     sums, N, NB);
  k_final<<<1, 64, 0, stream>>>(classSg, classCntg, sums, out, N, C);
}

// Round 16
// 124.224 us; speedup vs baseline: 1.3019x; 1.3019x over previous
//
#include <hip/hip_runtime.h>
#include <hip/hip_bf16.h>
#include <math.h>

// ---------------------------------------------------------------------------
// SupConLoss on MI355X.
// out = 0.5*CE(predicts,targets) + 0.5*nt_xent(Anorm, temp=0.1)
//       + 0.25*nt_xent2(Anorm, temp=0.05)
// Round 16: round-15 split-K x4 fp8 gemm + round-14 atomic-free tail.
// Round 15's k_merge did same-address GLOBAL float atomics (sums[0/1] from
// 1024 blocks -> serialized L2 round-trips, 55 us at 1% busy). Rule learned
// across rounds 10/15: cross-block same-address sync (fence or atomic) on
// non-coherent-XCD hardware costs tens of us — use stream order + plain
// stores instead.
//  - k_prep: vectorized normalize, fp8 fragment-pack, per-row CE.
//  - k_gemm_fused: 4 waves/tile split-K (6 iters each), 2-step LDS tree
//    exchange, epilogue split 4 ways. Register-direct packed loads.
//  - k_merge: per-row reduce of 64 partials -> psumRow/logS1/Srow stores.
//  - k_final: single block, LDS-atomic class histogram + final formula.
// NOTE: ~43 us of total is the harness's 268 MB d_ws re-poison fill — fixed.
// Exp sums unshifted (|exponent|<=20, fp32-safe); reference row-max shift
// applied exactly in merge: S_j = s2_raw * exp(-20*vmax_j).
// ---------------------------------------------------------------------------

typedef __attribute__((ext_vector_type(4))) float f32x4;
typedef long long ll;

__device__ __forceinline__ float blockReduceSum(float v, float* sbuf) {
#pragma unroll
  for (int o = 32; o > 0; o >>= 1) v += __shfl_down(v, o, 64);
  int lane = threadIdx.x & 63;
  int w = threadIdx.x >> 6;
  __syncthreads();
  if (lane == 0) sbuf[w] = v;
  __syncthreads();
  return sbuf[0] + sbuf[1] + sbuf[2] + sbuf[3];
}

// --- 1. fused normalize + fp8 fragment-pack + per-row CE -------------------
// Packed layout: 8B chunk index = ((strip*KB + kb)*4 + mt)*64 + lane
//   holds row = strip*64 + mt*16 + (lane&15), k = kb*32 + (lane>>4)*8 .. +7.
__global__ void k_prep(const float* __restrict__ X, const float* __restrict__ P,
                       const int* __restrict__ tgt, uint2* __restrict__ Pk,
                       float* __restrict__ ce_row, int D, int C) {
  __shared__ float sbuf[8];
  int row = blockIdx.x;
  const float* x = X + (size_t)row * D;
  float ss = 0.f;
  const float4* x4 = (const float4*)x;
  for (int j = threadIdx.x; j < (D >> 2); j += blockDim.x) {
    float4 v = x4[j];
    ss += v.x * v.x + v.y * v.y + v.z * v.z + v.w * v.w;
  }
  ss = blockReduceSum(ss, sbuf);
  float inv = 1.0f / fmaxf(sqrtf(ss), 1e-12f);

  const int KB = D / 32;           // 24
  const int strip = row >> 6;
  const int mt = (row >> 4) & 3;
  const int l4 = row & 15;
  const int nchunk = D / 8;        // 96
  for (int c = threadIdx.x; c < nchunk; c += blockDim.x) {
    int kb = c >> 2;
    int lsub = c & 3;
    int k0 = kb * 32 + lsub * 8;
    float v[8];
#pragma unroll
    for (int j = 0; j < 8; ++j) v[j] = x[k0 + j] * inv;
    unsigned int r0 = 0, r1 = 0;
    r0 = __builtin_amdgcn_cvt_pk_fp8_f32(v[0], v[1], r0, 0);
    r0 = __builtin_amdgcn_cvt_pk_fp8_f32(v[2], v[3], r0, 1);
    r1 = __builtin_amdgcn_cvt_pk_fp8_f32(v[4], v[5], r1, 0);
    r1 = __builtin_amdgcn_cvt_pk_fp8_f32(v[6], v[7], r1, 1);
    int lane = l4 + 16 * lsub;
    size_t chunk = ((size_t)(strip * KB + kb) * 4 + mt) * 64 + lane;
    Pk[chunk] = make_uint2(r0, r1);
  }
  if (threadIdx.x == 0) {
    const float* p = P + (size_t)row * C;
    float m = -INFINITY;
    for (int c = 0; c < C; ++c) m = fmaxf(m, p[c]);
    float s = 0.f;
    for (int c = 0; c < C; ++c) s += expf(p[c] - m);
    int t = tgt[row];
    ce_row[row] = -(p[t] - m - logf(s));
  }
}

// --- 2. 4-wave split-K 64x64 fused symmetric GEMM + stats, fp8 packed ------
// part layout: float4 part[N][NB]; (psum, s1_raw, s2_raw, m2=20*vmax_neg).
__global__ __launch_bounds__(256) void k_gemm_fused(
    const unsigned char* __restrict__ Pk, const int* __restrict__ lab,
    float4* __restrict__ part, int N, int K, int NB) {
  __shared__ f32x4 buf0[4][4][64];  // 16 KB
  __shared__ f32x4 buf1[4][4][64];  // 16 KB

  // triangular decode: bid -> (by, bx), by >= bx
  int bid = blockIdx.x;
  int by = (int)((sqrtf(8.f * (float)bid + 1.f) - 1.f) * 0.5f);
  while ((by + 1) * (by + 2) / 2 <= bid) ++by;
  while (by * (by + 1) / 2 > bid) --by;
  int bx = bid - by * (by + 1) / 2;

  const int t = threadIdx.x & 63;
  const int wv = threadIdx.x >> 6;  // 0..3
  const int rowBase = by * 64;
  const int colBase = bx * 64;
  const int KB = K / 32;        // 24
  const int KBq = KB >> 2;      // 6 per wave

  const int myLR = lab[rowBase + t];
  const int myLC = lab[colBase + t];

  // byte offsets: chunk = ((strip*KB+kb)*4+mt)*64 + lane, 8 bytes each;
  // this wave's K-quarter starts at kb = wv*KBq.
  const unsigned char* aP =
      Pk + ((size_t)by * KB * 4 * 64 + t) * 8 + (size_t)wv * KBq * 2048;
  const unsigned char* bP =
      Pk + ((size_t)bx * KB * 4 * 64 + t) * 8 + (size_t)wv * KBq * 2048;

  f32x4 acc[4][4] = {};
#pragma unroll 2
  for (int kb = 0; kb < KBq; ++kb) {
    ll af[4], bf[4];
    const unsigned char* ak = aP + (size_t)kb * 2048;
    const unsigned char* bk = bP + (size_t)kb * 2048;
#pragma unroll
    for (int mt = 0; mt < 4; ++mt) af[mt] = *(const ll*)(ak + mt * 512);
#pragma unroll
    for (int nt = 0; nt < 4; ++nt) bf[nt] = *(const ll*)(bk + nt * 512);
#pragma unroll
    for (int mt = 0; mt < 4; ++mt)
#pragma unroll
      for (int nt = 0; nt < 4; ++nt)
        acc[mt][nt] = __builtin_amdgcn_mfma_f32_16x16x32_fp8_fp8(
            af[mt], bf[nt], acc[mt][nt], 0, 0, 0);
  }

  // ---- 2-step tree exchange: buf0 = w0+w1, buf1 = w2+w3 ------------------
  if (wv == 0) {
#pragma unroll
    for (int mt = 0; mt < 4; ++mt)
#pragma unroll
      for (int nt = 0; nt < 4; ++nt) buf0[mt][nt][t] = acc[mt][nt];
  } else if (wv == 2) {
#pragma unroll
    for (int mt = 0; mt < 4; ++mt)
#pragma unroll
      for (int nt = 0; nt < 4; ++nt) buf1[mt][nt][t] = acc[mt][nt];
  }
  __syncthreads();
  if (wv == 1) {
#pragma unroll
    for (int mt = 0; mt < 4; ++mt)
#pragma unroll
      for (int nt = 0; nt < 4; ++nt) {
        acc[mt][nt] += buf0[mt][nt][t];
        buf0[mt][nt][t] = acc[mt][nt];
      }
  } else if (wv == 3) {
#pragma unroll
    for (int mt = 0; mt < 4; ++mt)
#pragma unroll
      for (int nt = 0; nt < 4; ++nt) {
        acc[mt][nt] += buf1[mt][nt][t];
        buf1[mt][nt][t] = acc[mt][nt];
      }
  }
  __syncthreads();

  // ---- epilogue: w0/w1 = A-side (mt pairs), w2/w3 = B-side (nt pairs) -----
  // element: row = mt*16 + (t>>4)*4 + r ; col = nt*16 + (t&15)
  int cl[4];
#pragma unroll
  for (int nt = 0; nt < 4; ++nt) cl[nt] = __shfl(myLC, nt * 16 + (t & 15), 64);
  const bool dg = (by == bx);

  if (wv < 2) {
    f32x4 fq[2][4];
#pragma unroll
    for (int mi = 0; mi < 2; ++mi) {
      int mt = wv * 2 + mi;
#pragma unroll
      for (int nt = 0; nt < 4; ++nt)
        fq[mi][nt] = buf0[mt][nt][t] + buf1[mt][nt][t];
    }
#pragma unroll
    for (int mi = 0; mi < 2; ++mi) {
      int mt = wv * 2 + mi;
#pragma unroll
      for (int r = 0; r < 4; ++r) {
        int rowL = mt * 16 + (t >> 4) * 4 + r;
        int lr = __shfl(myLR, rowL, 64);
        float ps = 0.f, s1 = 0.f, s2 = 0.f, vm = -1e30f;
#pragma unroll
        for (int nt = 0; nt < 4; ++nt) {
          float v = fq[mi][nt][r];
          int colL = nt * 16 + (t & 15);
          bool diag = dg && (rowL == colL);
          bool same = (lr == cl[nt]);
          float e10 = __expf(v * 10.f);
          float e20 = e10 * e10;
          s1 += diag ? 1.f : e10;
          ps += (same && !diag) ? v : 0.f;
          s2 += same ? 0.f : e20;
          vm = same ? vm : fmaxf(vm, v);
        }
#pragma unroll
        for (int o = 1; o < 16; o <<= 1) {
          ps += __shfl_xor(ps, o, 64);
          s1 += __shfl_xor(s1, o, 64);
          s2 += __shfl_xor(s2, o, 64);
          vm = fmaxf(vm, __shfl_xor(vm, o, 64));
        }
        if ((t & 15) == 0)
          part[(size_t)(rowBase + rowL) * NB + bx] =
              make_float4(ps, s1, s2, 20.f * vm);
      }
    }
  } else if (!dg) {
    f32x4 fq[4][2];
#pragma unroll
    for (int ni = 0; ni < 2; ++ni) {
      int nt = (wv - 2) * 2 + ni;
#pragma unroll
      for (int mt = 0; mt < 4; ++mt)
        fq[mt][ni] = buf0[mt][nt][t] + buf1[mt][nt][t];
    }
#pragma unroll
    for (int ni = 0; ni < 2; ++ni) {
      int nt = (wv - 2) * 2 + ni;
      int lc = cl[nt];
      float ps = 0.f, s1 = 0.f, s2 = 0.f, vm = -1e30f;
#pragma unroll
      for (int mt = 0; mt < 4; ++mt)
#pragma unroll
        for (int r = 0; r < 4; ++r) {
          float v = fq[mt][ni][r];
          int rowL = mt * 16 + (t >> 4) * 4 + r;
          int lr = __shfl(myLR, rowL, 64);
          bool same = (lr == lc);
          float e10 = __expf(v * 10.f);
          s1 += e10;
          ps += same ? v : 0.f;
          s2 += same ? 0.f : e10 * e10;
          vm = same ? vm : fmaxf(vm, v);
        }
#pragma unroll
      for (int o = 16; o < 64; o <<= 1) {
        ps += __shfl_xor(ps, o, 64);
        s1 += __shfl_xor(s1, o, 64);
        s2 += __shfl_xor(s2, o, 64);
        vm = fmaxf(vm, __shfl_xor(vm, o, 64));
      }
      if ((t >> 4) == 0)
        part[(size_t)(colBase + nt * 16 + (t & 15)) * NB + by] =
            make_float4(ps, s1, s2, 20.f * vm);
    }
  }
}

// --- 3. merge partials per row (no atomics: plain stores) ------------------
__global__ void k_merge(const float4* __restrict__ part,
                        float* __restrict__ psumRow,
                        float* __restrict__ logS1, float* __restrict__ Srow,
                        int N, int NB) {
  int lane = threadIdx.x & 63;
  int w = threadIdx.x >> 6;
  int row = blockIdx.x * 4 + w;
  float ps = 0.f, s1 = 0.f, s2 = 0.f, m2 = -1e30f;
  if (lane < NB) {
    float4 p = part[(size_t)row * NB + lane];
    ps = p.x; s1 = p.y; s2 = p.z; m2 = p.w;
  }
#pragma unroll
  for (int o = 32; o > 0; o >>= 1) {
    ps += __shfl_down(ps, o, 64);
    s1 += __shfl_down(s1, o, 64);
    s2 += __shfl_down(s2, o, 64);
    m2 = fmaxf(m2, __shfl_down(m2, o, 64));
  }
  if (lane == 0) {
    psumRow[row] = ps;
    logS1[row] = logf(s1);
    Srow[row] = (m2 < -1e29f) ? 0.f : s2 * expf(-m2);
  }
}

// --- 4. finalize (single block; LDS atomics only — cheap) ------------------
__global__ void k_final(const float* __restrict__ ce_row,
                        const float* __restrict__ psumRow,
                        const float* __restrict__ logS1,
                        const float* __restrict__ Srow,
                        const int* __restrict__ lab, float* __restrict__ out,
                        int N, int C) {
  __shared__ float classS[32];
  __shared__ int classCnt[32];
  __shared__ float sbuf[8];
  if (threadIdx.x < 32) {
    classS[threadIdx.x] = 0.f;
    classCnt[threadIdx.x] = 0;
  }
  __syncthreads();
  float sumCe = 0.f;
  for (int i = threadIdx.x; i < N; i += blockDim.x) {
    sumCe += ce_row[i];
    int l = lab[i];
    atomicAdd(&classCnt[l], 1);
    atomicAdd(&classS[l], Srow[i]);
  }
  __syncthreads();
  float sumP1 = 0.f;
  for (int i = threadIdx.x; i < N; i += blockDim.x) {
    int l = lab[i];
    int pc = classCnt[l] - 1;
    if (pc > 0) sumP1 += psumRow[i] * 10.f / (float)pc - logS1[i];
  }
  sumCe = blockReduceSum(sumCe, sbuf);
  sumP1 = blockReduceSum(sumP1, sbuf);
  if (threadIdx.x == 0) {
    float totS = 0.f;
    for (int c = 0; c < C; ++c) totS += classS[c];
    float l2sum = 0.f;
    for (int c = 0; c < C; ++c) {
      int cnt = classCnt[c];
      if (cnt >= 2) {
        float negs = (float)(N - cnt);
        float x = (totS - classS[c]) / negs;
        l2sum += (float)cnt * logf(x + 1e-12f);
      }
    }
    float ce = sumCe / (float)N;
    float ntx1 = -sumP1 / (float)N;
    float ntx2 = l2sum / (float)N;
    out[0] = 0.5f * ce + 0.5f * ntx1 + 0.25f * ntx2;
  }
}

extern "C" void kernel_launch(void* const* d_in, const int* in_sizes, int n_in,
                              void* d_out, int out_size, void* d_ws,
                              size_t ws_size, hipStream_t stream) {
  const float* X = (const float*)d_in[0];  // cls_feats [N,D]
  const float* P = (const float*)d_in[1];  // predicts  [N,C]
  const int* tgt = (const int*)d_in[2];    // targets   [N]
  float* out = (float*)d_out;

  int N = in_sizes[2];
  int D = in_sizes[0] / N;
  int C = in_sizes[1] / N;
  int NB = N / 64;

  char* ws = (char*)d_ws;
  uint2* Pk = (uint2*)ws;                        // N*D fp8 bytes, packed
  float4* part = (float4*)(ws + (size_t)N * D);  // N*NB float4
  float* ce_row = (float*)((char*)part + (size_t)N * NB * 16);
  float* psumRow = ce_row + N;
  float* logS1 = psumRow + N;
  float* Srow = logS1 + N;

  k_prep<<<N, 256, 0, stream>>>(X, P, tgt, Pk, ce_row, D, C);
  int nblk = NB * (NB + 1) / 2;
  k_gemm_fused<<<nblk, 256, 0, stream>>>((const unsigned char*)Pk, tgt, part,
                                         N, D, NB);
  k_merge<<<N / 4, 256, 0, stream>>>(part, psumRow, logS1, Srow, N, NB);
  k_final<<<1, 256, 0, stream>>>(ce_row, psumRow, logS1, Srow, tgt, out, N, C);
}

// Round 17
// 118.417 us; speedup vs baseline: 1.3657x; 1.0490x over previous
//
#include <hip/hip_runtime.h>
#include <hip/hip_bf16.h>
#include <math.h>

// ---------------------------------------------------------------------------
// SupConLoss on MI355X.
// out = 0.5*CE(predicts,targets) + 0.5*nt_xent(Anorm, temp=0.1)
//       + 0.25*nt_xent2(Anorm, temp=0.05)
// Round 17: round-16 split-K x4 fp8 gemm (untouched — best measured) with a
// slimmer tail:
//  - k_prep: wave-per-row (1024 blocks x 4 waves, no barriers), float4
//    loads, wave-shuffle norm reduce; block 0 also histograms targets into
//    classCnt via LDS int atomics (cheap; round 15's disaster was GLOBAL
//    float atomics, not LDS).
//  - k_merge: per-row reduce of 64 partials, then per-BLOCK partials
//    (sum_ce, sum_p1, classS[10]) via plain stores — no global atomics.
//  - k_final: reduce 1024x12 partials (was: 4096-row scan + 8192 LDS
//    atomics).
// NOTE: ~41 us of total is the harness's 268 MB d_ws re-poison fill — fixed
// cost, visible as fillBufferAligned, not addressable from kernel code.
// Exp sums unshifted (|exponent|<=20, fp32-safe); reference row-max shift
// applied exactly in merge: S_j = s2_raw * exp(-20*vmax_j).
// ---------------------------------------------------------------------------

typedef __attribute__((ext_vector_type(4))) float f32x4;
typedef long long ll;

__device__ __forceinline__ float blockReduceSum(float v, float* sbuf) {
#pragma unroll
  for (int o = 32; o > 0; o >>= 1) v += __shfl_down(v, o, 64);
  int lane = threadIdx.x & 63;
  int w = threadIdx.x >> 6;
  __syncthreads();
  if (lane == 0) sbuf[w] = v;
  __syncthreads();
  return sbuf[0] + sbuf[1] + sbuf[2] + sbuf[3];
}

// --- 1. normalize + fp8 fragment-pack + CE, wave-per-row; blk0 histogram ---
// Packed layout: 8B chunk index = ((strip*KB + kb)*4 + mt)*64 + lane
//   holds row = strip*64 + mt*16 + (lane&15), k = kb*32 + (lane>>4)*8 .. +7.
__global__ void k_prep(const float* __restrict__ X, const float* __restrict__ P,
                       const int* __restrict__ tgt, uint2* __restrict__ Pk,
                       float* __restrict__ ce_row, int* __restrict__ classCnt,
                       int N, int D, int C) {
  const int lane = threadIdx.x & 63;
  const int w = threadIdx.x >> 6;
  const int row = blockIdx.x * 4 + w;

  const float* x = X + (size_t)row * D;
  const float4* x4 = (const float4*)x;
  float ss = 0.f;
  for (int j = lane; j < (D >> 2); j += 64) {
    float4 v = x4[j];
    ss += v.x * v.x + v.y * v.y + v.z * v.z + v.w * v.w;
  }
#pragma unroll
  for (int o = 1; o < 64; o <<= 1) ss += __shfl_xor(ss, o, 64);
  float inv = 1.0f / fmaxf(sqrtf(ss), 1e-12f);

  const int KB = D / 32;           // 24
  const int strip = row >> 6;
  const int mt = (row >> 4) & 3;
  const int l4 = row & 15;
  const int nchunk = D / 8;        // 96
  for (int c = lane; c < nchunk; c += 64) {
    int kb = c >> 2;
    int lsub = c & 3;
    int k0 = kb * 32 + lsub * 8;
    float4 v0 = x4[k0 >> 2];
    float4 v1 = x4[(k0 >> 2) + 1];
    unsigned int r0 = 0, r1 = 0;
    r0 = __builtin_amdgcn_cvt_pk_fp8_f32(v0.x * inv, v0.y * inv, r0, 0);
    r0 = __builtin_amdgcn_cvt_pk_fp8_f32(v0.z * inv, v0.w * inv, r0, 1);
    r1 = __builtin_amdgcn_cvt_pk_fp8_f32(v1.x * inv, v1.y * inv, r1, 0);
    r1 = __builtin_amdgcn_cvt_pk_fp8_f32(v1.z * inv, v1.w * inv, r1, 1);
    int plane = l4 + 16 * lsub;
    size_t chunk = ((size_t)(strip * KB + kb) * 4 + mt) * 64 + plane;
    Pk[chunk] = make_uint2(r0, r1);
  }
  if (lane == 0) {
    const float* p = P + (size_t)row * C;
    float m = -INFINITY;
    for (int c = 0; c < C; ++c) m = fmaxf(m, p[c]);
    float s = 0.f;
    for (int c = 0; c < C; ++c) s += expf(p[c] - m);
    int t = tgt[row];
    ce_row[row] = -(p[t] - m - logf(s));
  }
  // block 0: class histogram (LDS int atomics — cheap)
  if (blockIdx.x == 0) {
    __shared__ int hc[32];
    if (threadIdx.x < 32) hc[threadIdx.x] = 0;
    __syncthreads();
    for (int i = threadIdx.x; i < N; i += blockDim.x)
      atomicAdd(&hc[tgt[i]], 1);
    __syncthreads();
    if (threadIdx.x < C) classCnt[threadIdx.x] = hc[threadIdx.x];
  }
}

// --- 2. 4-wave split-K 64x64 fused symmetric GEMM + stats, fp8 packed ------
// part layout: float4 part[N][NB]; (psum, s1_raw, s2_raw, m2=20*vmax_neg).
__global__ __launch_bounds__(256) void k_gemm_fused(
    const unsigned char* __restrict__ Pk, const int* __restrict__ lab,
    float4* __restrict__ part, int N, int K, int NB) {
  __shared__ f32x4 buf0[4][4][64];  // 16 KB
  __shared__ f32x4 buf1[4][4][64];  // 16 KB

  // triangular decode: bid -> (by, bx), by >= bx
  int bid = blockIdx.x;
  int by = (int)((sqrtf(8.f * (float)bid + 1.f) - 1.f) * 0.5f);
  while ((by + 1) * (by + 2) / 2 <= bid) ++by;
  while (by * (by + 1) / 2 > bid) --by;
  int bx = bid - by * (by + 1) / 2;

  const int t = threadIdx.x & 63;
  const int wv = threadIdx.x >> 6;  // 0..3
  const int rowBase = by * 64;
  const int colBase = bx * 64;
  const int KB = K / 32;        // 24
  const int KBq = KB >> 2;      // 6 per wave

  const int myLR = lab[rowBase + t];
  const int myLC = lab[colBase + t];

  const unsigned char* aP =
      Pk + ((size_t)by * KB * 4 * 64 + t) * 8 + (size_t)wv * KBq * 2048;
  const unsigned char* bP =
      Pk + ((size_t)bx * KB * 4 * 64 + t) * 8 + (size_t)wv * KBq * 2048;

  f32x4 acc[4][4] = {};
#pragma unroll 2
  for (int kb = 0; kb < KBq; ++kb) {
    ll af[4], bf[4];
    const unsigned char* ak = aP + (size_t)kb * 2048;
    const unsigned char* bk = bP + (size_t)kb * 2048;
#pragma unroll
    for (int mt = 0; mt < 4; ++mt) af[mt] = *(const ll*)(ak + mt * 512);
#pragma unroll
    for (int nt = 0; nt < 4; ++nt) bf[nt] = *(const ll*)(bk + nt * 512);
#pragma unroll
    for (int mt = 0; mt < 4; ++mt)
#pragma unroll
      for (int nt = 0; nt < 4; ++nt)
        acc[mt][nt] = __builtin_amdgcn_mfma_f32_16x16x32_fp8_fp8(
            af[mt], bf[nt], acc[mt][nt], 0, 0, 0);
  }

  // ---- 2-step tree exchange: buf0 = w0+w1, buf1 = w2+w3 ------------------
  if (wv == 0) {
#pragma unroll
    for (int mt = 0; mt < 4; ++mt)
#pragma unroll
      for (int nt = 0; nt < 4; ++nt) buf0[mt][nt][t] = acc[mt][nt];
  } else if (wv == 2) {
#pragma unroll
    for (int mt = 0; mt < 4; ++mt)
#pragma unroll
      for (int nt = 0; nt < 4; ++nt) buf1[mt][nt][t] = acc[mt][nt];
  }
  __syncthreads();
  if (wv == 1) {
#pragma unroll
    for (int mt = 0; mt < 4; ++mt)
#pragma unroll
      for (int nt = 0; nt < 4; ++nt) {
        acc[mt][nt] += buf0[mt][nt][t];
        buf0[mt][nt][t] = acc[mt][nt];
      }
  } else if (wv == 3) {
#pragma unroll
    for (int mt = 0; mt < 4; ++mt)
#pragma unroll
      for (int nt = 0; nt < 4; ++nt) {
        acc[mt][nt] += buf1[mt][nt][t];
        buf1[mt][nt][t] = acc[mt][nt];
      }
  }
  __syncthreads();

  // ---- epilogue: w0/w1 = A-side (mt pairs), w2/w3 = B-side (nt pairs) -----
  int cl[4];
#pragma unroll
  for (int nt = 0; nt < 4; ++nt) cl[nt] = __shfl(myLC, nt * 16 + (t & 15), 64);
  const bool dg = (by == bx);

  if (wv < 2) {
    f32x4 fq[2][4];
#pragma unroll
    for (int mi = 0; mi < 2; ++mi) {
      int mt = wv * 2 + mi;
#pragma unroll
      for (int nt = 0; nt < 4; ++nt)
        fq[mi][nt] = buf0[mt][nt][t] + buf1[mt][nt][t];
    }
#pragma unroll
    for (int mi = 0; mi < 2; ++mi) {
      int mt = wv * 2 + mi;
#pragma unroll
      for (int r = 0; r < 4; ++r) {
        int rowL = mt * 16 + (t >> 4) * 4 + r;
        int lr = __shfl(myLR, rowL, 64);
        float ps = 0.f, s1 = 0.f, s2 = 0.f, vm = -1e30f;
#pragma unroll
        for (int nt = 0; nt < 4; ++nt) {
          float v = fq[mi][nt][r];
          int colL = nt * 16 + (t & 15);
          bool diag = dg && (rowL == colL);
          bool same = (lr == cl[nt]);
          float e10 = __expf(v * 10.f);
          float e20 = e10 * e10;
          s1 += diag ? 1.f : e10;
          ps += (same && !diag) ? v : 0.f;
          s2 += same ? 0.f : e20;
          vm = same ? vm : fmaxf(vm, v);
        }
#pragma unroll
        for (int o = 1; o < 16; o <<= 1) {
          ps += __shfl_xor(ps, o, 64);
          s1 += __shfl_xor(s1, o, 64);
          s2 += __shfl_xor(s2, o, 64);
          vm = fmaxf(vm, __shfl_xor(vm, o, 64));
        }
        if ((t & 15) == 0)
          part[(size_t)(rowBase + rowL) * NB + bx] =
              make_float4(ps, s1, s2, 20.f * vm);
      }
    }
  } else if (!dg) {
    f32x4 fq[4][2];
#pragma unroll
    for (int ni = 0; ni < 2; ++ni) {
      int nt = (wv - 2) * 2 + ni;
#pragma unroll
      for (int mt = 0; mt < 4; ++mt)
        fq[mt][ni] = buf0[mt][nt][t] + buf1[mt][nt][t];
    }
#pragma unroll
    for (int ni = 0; ni < 2; ++ni) {
      int nt = (wv - 2) * 2 + ni;
      int lc = cl[nt];
      float ps = 0.f, s1 = 0.f, s2 = 0.f, vm = -1e30f;
#pragma unroll
      for (int mt = 0; mt < 4; ++mt)
#pragma unroll
        for (int r = 0; r < 4; ++r) {
          float v = fq[mt][ni][r];
          int rowL = mt * 16 + (t >> 4) * 4 + r;
          int lr = __shfl(myLR, rowL, 64);
          bool same = (lr == lc);
          float e10 = __expf(v * 10.f);
          s1 += e10;
          ps += same ? v : 0.f;
          s2 += same ? 0.f : e10 * e10;
          vm = same ? vm : fmaxf(vm, v);
        }
#pragma unroll
      for (int o = 16; o < 64; o <<= 1) {
        ps += __shfl_xor(ps, o, 64);
        s1 += __shfl_xor(s1, o, 64);
        s2 += __shfl_xor(s2, o, 64);
        vm = fmaxf(vm, __shfl_xor(vm, o, 64));
      }
      if ((t >> 4) == 0)
        part[(size_t)(colBase + nt * 16 + (t & 15)) * NB + by] =
            make_float4(ps, s1, s2, 20.f * vm);
    }
  }
}

// --- 3. merge partials per row -> per-block partial sums (plain stores) ----
__global__ void k_merge(const float4* __restrict__ part,
                        const float* __restrict__ ce_row,
                        const int* __restrict__ lab,
                        const int* __restrict__ classCnt,
                        float2* __restrict__ partial2,
                        float* __restrict__ partialS, int N, int NB, int C) {
  __shared__ float srowA[4], ceA[4], p1A[4];
  __shared__ int labA[4];
  int lane = threadIdx.x & 63;
  int w = threadIdx.x >> 6;
  int row = blockIdx.x * 4 + w;
  float ps = 0.f, s1 = 0.f, s2 = 0.f, m2 = -1e30f;
  if (lane < NB) {
    float4 p = part[(size_t)row * NB + lane];
    ps = p.x; s1 = p.y; s2 = p.z; m2 = p.w;
  }
#pragma unroll
  for (int o = 32; o > 0; o >>= 1) {
    ps += __shfl_down(ps, o, 64);
    s1 += __shfl_down(s1, o, 64);
    s2 += __shfl_down(s2, o, 64);
    m2 = fmaxf(m2, __shfl_down(m2, o, 64));
  }
  if (lane == 0) {
    int l = lab[row];
    float Srow = (m2 < -1e29f) ? 0.f : s2 * expf(-m2);
    int pc = classCnt[l] - 1;
    float p1 = (pc > 0) ? ps * 10.f / (float)pc - logf(s1) : 0.f;
    srowA[w] = Srow;
    labA[w] = l;
    ceA[w] = ce_row[row];
    p1A[w] = p1;
  }
  __syncthreads();
  int t = threadIdx.x;
  if (t < C) {
    float s = 0.f;
#pragma unroll
    for (int i = 0; i < 4; ++i) s += (labA[i] == t) ? srowA[i] : 0.f;
    partialS[blockIdx.x * 16 + t] = s;
  } else if (t == 16) {
    partial2[blockIdx.x] = make_float2(ceA[0] + ceA[1] + ceA[2] + ceA[3],
                                       p1A[0] + p1A[1] + p1A[2] + p1A[3]);
  }
}

// --- 4. finalize: reduce 1024x(2+10) partials + formula --------------------
__global__ void k_final(const float2* __restrict__ partial2,
                        const float* __restrict__ partialS,
                        const int* __restrict__ classCnt,
                        float* __restrict__ out, int NBLK, int N, int C) {
  __shared__ float sbuf[8];
  __shared__ float cls[32];
  float ce = 0.f, p1 = 0.f;
  for (int b = threadIdx.x; b < NBLK; b += blockDim.x) {
    float2 v = partial2[b];
    ce += v.x;
    p1 += v.y;
  }
  ce = blockReduceSum(ce, sbuf);
  p1 = blockReduceSum(p1, sbuf);
  for (int c = 0; c < C; ++c) {
    float s = 0.f;
    for (int b = threadIdx.x; b < NBLK; b += blockDim.x)
      s += partialS[b * 16 + c];
    s = blockReduceSum(s, sbuf);
    if (threadIdx.x == 0) cls[c] = s;
  }
  __syncthreads();
  if (threadIdx.x == 0) {
    float totS = 0.f;
    for (int c = 0; c < C; ++c) totS += cls[c];
    float l2sum = 0.f;
    for (int c = 0; c < C; ++c) {
      int cnt = classCnt[c];
      if (cnt >= 2) {
        float negs = (float)(N - cnt);
        float x = (totS - cls[c]) / negs;
        l2sum += (float)cnt * logf(x + 1e-12f);
      }
    }
    float cem = ce / (float)N;
    float ntx1 = -p1 / (float)N;
    float ntx2 = l2sum / (float)N;
    out[0] = 0.5f * cem + 0.5f * ntx1 + 0.25f * ntx2;
  }
}

extern "C" void kernel_launch(void* const* d_in, const int* in_sizes, int n_in,
                              void* d_out, int out_size, void* d_ws,
                              size_t ws_size, hipStream_t stream) {
  const float* X = (const float*)d_in[0];  // cls_feats [N,D]
  const float* P = (const float*)d_in[1];  // predicts  [N,C]
  const int* tgt = (const int*)d_in[2];    // targets   [N]
  float* out = (float*)d_out;

  int N = in_sizes[2];
  int D = in_sizes[0] / N;
  int C = in_sizes[1] / N;
  int NB = N / 64;
  int NBLK = N / 4;

  char* ws = (char*)d_ws;
  uint2* Pk = (uint2*)ws;                        // N*D fp8 bytes, packed
  float4* part = (float4*)(ws + (size_t)N * D);  // N*NB float4
  float* ce_row = (float*)((char*)part + (size_t)N * NB * 16);
  int* classCnt = (int*)(ce_row + N);            // 32
  float2* partial2 = (float2*)(classCnt + 32);   // NBLK float2
  float* partialS = (float*)(partial2 + NBLK);   // NBLK*16 floats

  k_prep<<<NBLK, 256, 0, stream>>>(X, P, tgt, Pk, ce_row, classCnt, N, D, C);
  int nblk = NB * (NB + 1) / 2;
  k_gemm_fused<<<nblk, 256, 0, stream>>>((const unsigned char*)Pk, tgt, part,
                                         N, D, NB);
  k_merge<<<NBLK, 256, 0, stream>>>(part, ce_row, tgt, classCnt, partial2,
                                    partialS, N, NB, C);
  k_final<<<1, 256, 0, stream>>>(partial2, partialS, classCnt, out, NBLK, N,
                                 C);
}